// Round 11
// baseline (352.314 us; speedup 1.0000x reference)
//
#include <hip/hip_runtime.h>
#include <stdint.h>

#define EFFECT_DIM 758
#define ADD_DIM 10
#define EMBED_DIM 768
#define NCOLS 95000
#define NSYN 8
#define NROWS 1024
#define TILE_B 32768         // bytes per 256x64 bf16 A tile (fragment-ordered)
#define NTN 743              // n-tiles of 128
#define NWG (2 * NTN)        // 1486 blocks (mt 2 x nt 743)

typedef __attribute__((ext_vector_type(8))) __bf16 bf16x8;
typedef __attribute__((ext_vector_type(16))) float f32x16;
typedef __attribute__((ext_vector_type(4))) uint32_t u32x4;

// Fragment order (16-k block): frag = 1KB, lane = (row&31) + (khalf8<<5),
// 16B/lane = 8 consecutive k as bf16. A tile (ws): tile(mtq,ks) at
// (mtq*12+ks)*32768; + kk*8192 + grp*1024 + lane*16.

static __device__ __forceinline__ uint32_t pack2(float a, float b) {
  uint32_t r;
  asm("v_cvt_pk_bf16_f32 %0, %1, %2" : "=v"(r) : "v"(a), "v"(b));
  return r;
}

// ---------------------------------------------------------------------------
// Kernel 1: VirtualEmbedding -> bf16 A tiles (4 m-tiles x 12 ks), frag order.
// (unchanged — verified R9/R10)
// ---------------------------------------------------------------------------
__global__ __launch_bounds__(256) void emb_kernel(
    const int* __restrict__ ids, const float* __restrict__ W_emb,
    const float* __restrict__ padding, const int* __restrict__ syn_table,
    const int* __restrict__ syn_mask, char* __restrict__ ws)
{
  const int l = blockIdx.x;
  const int t = threadIdx.x;
  const int id = ids[l];
  int sid[NSYN];
  int msk[NSYN];
#pragma unroll
  for (int k = 0; k < NSYN; ++k) {
    sid[k] = syn_table[id * NSYN + k];
    msk[k] = syn_mask[id * NSYN + k];
  }

  double p[9] = {0, 0, 0, 0, 0, 0, 0, 0, 0};
  for (int d = t; d < EFFECT_DIM; d += 256) {
    p[0] += (double)W_emb[(size_t)id * EFFECT_DIM + d];
#pragma unroll
    for (int k = 0; k < NSYN; ++k)
      p[k + 1] += (double)W_emb[(size_t)sid[k] * EFFECT_DIM + d];
  }

  __shared__ double s_red[9][4];
  const int w = t >> 6;
#pragma unroll
  for (int k = 0; k < 9; ++k) {
    double v = p[k];
#pragma unroll
    for (int off = 32; off > 0; off >>= 1) v += __shfl_down(v, off, 64);
    if ((t & 63) == 0) s_red[k][w] = v;
  }
  __syncthreads();

  const double isum = s_red[0][0] + s_red[0][1] + s_red[0][2] + s_red[0][3];
  float coef[NSYN];
#pragma unroll
  for (int k = 0; k < NSYN; ++k) {
    double ss = s_red[k + 1][0] + s_red[k + 1][1] + s_red[k + 1][2] + s_red[k + 1][3];
    coef[k] = msk[k] ? (float)(isum / ss) : 0.0f;
  }

  const int r = l & 255;
  char* wbase = ws + (size_t)(l >> 8) * (12 * TILE_B);

  for (int j = t; j < 384; j += 256) {
    const int d0 = 2 * j;
    float v0, v1;
    if (d0 < EFFECT_DIM) {
      const float* bp = W_emb + (size_t)id * EFFECT_DIM + d0;
      v0 = bp[0];
      v1 = bp[1];
#pragma unroll
      for (int k = 0; k < NSYN; ++k) {
        const float* sp = W_emb + (size_t)sid[k] * EFFECT_DIM + d0;
        v0 = fmaf(coef[k], sp[0], v0);
        v1 = fmaf(coef[k], sp[1], v1);
      }
    } else {
      v0 = padding[l * ADD_DIM + (d0 - EFFECT_DIM)];
      v1 = padding[l * ADD_DIM + (d0 + 1 - EFFECT_DIM)];
    }
    const int ks   = j >> 5;
    const int jl   = j & 31;
    const int kk   = jl >> 3;
    const int byte = (jl & 7) * 4;
    const int lane = (r & 31) + ((byte >> 4) << 5);
    *(uint32_t*)(wbase + ks * TILE_B + kk * 8192 + (r >> 5) * 1024 +
                 lane * 16 + (byte & 15)) = pack2(v0, v1);
  }
}

// ---------------------------------------------------------------------------
// Kernel 2 (fused, R11): M512 x N128 block, 512 threads, 8 waves =
// 4 m-slices(128 rows) x 2 n-halves(64 cols); wave acc[4][2] (128 VGPR).
// Per ks (K=64): B chunk 128n x 64k staged f32->bf16 into 16KB LDS frag
// layout [kk4][ng4][lane64]x16B, double-buffered; f32 prefetched to regs
// one ks ahead (T14). A frags stream global->VGPR (L2-hot, frag-ordered,
// no LDS/no sync). ONE __syncthreads per ks, and all VMEM is retired by
// data deps before it -> no stage-drain stall. No conv pass.
// ---------------------------------------------------------------------------
__global__ __launch_bounds__(512, 2) void gemm_fused(
    const float* __restrict__ Wrev, const char* __restrict__ Abuf,
    float* __restrict__ out)
{
  __shared__ char lds[32768];  // 2 x 16KB B buffers
  const int t = threadIdx.x;
  const int l = t & 63;
  const int w = t >> 6;
  const int ms = w >> 1;       // 0..3: which 128-row m-slice
  const int nh = w & 1;        // 0..1: which 64-col n-half

  // bijective XCD remap (m204): NWG=1486, q=185, r=6
  const int orig  = blockIdx.x;
  const int xcd   = orig & 7;
  const int local = orig >> 3;
  const int chunk0 = (xcd < 6) ? xcd * 186 : 6 * 186 + (xcd - 6) * 185;
  const int work = chunk0 + local;
  const int mt = work & 1;     // siblings (same nt) adjacent -> B L2-shared
  const int nt = work >> 1;
  const int n0 = nt * 128;

  // staging role: thread owns (n = t&127, kg = t>>7) -> 16 k-rows
  const int sn = t & 127;
  const int kg = t >> 7;       // 0..3 == kk block
  const int gn = n0 + sn;
  const bool valid = gn < NCOLS;
  const int swlane = sn & 31;
  char* const bB = (char*)lds + kg * 4096 + (sn >> 5) * 1024;

  float br[16];

#define BLOAD(ksi)                                                        \
  {                                                                       \
    const float* p = Wrev + (size_t)((ksi) * 64 + kg * 16) * NCOLS + gn;  \
    _Pragma("unroll") for (int j = 0; j < 16; ++j)                        \
      br[j] = valid ? p[(size_t)j * NCOLS] : 0.0f;                        \
  }

#define BSTORE(buf)                                                       \
  {                                                                       \
    u32x4 u0, u1;                                                         \
    _Pragma("unroll") for (int j = 0; j < 4; ++j) {                       \
      u0[j] = pack2(br[2 * j], br[2 * j + 1]);                            \
      u1[j] = pack2(br[8 + 2 * j], br[9 + 2 * j]);                        \
    }                                                                     \
    char* bb = bB + (buf) * 16384;                                        \
    *(u32x4*)(bb + swlane * 16) = u0;                                     \
    *(u32x4*)(bb + (swlane + 32) * 16) = u1;                              \
  }

  // prologue: B(0) -> buf0
  BLOAD(0);
  BSTORE(0);
  __syncthreads();

  const int mtq = mt * 2 + (ms >> 1);
  const char* abase =
      Abuf + (size_t)mtq * (12 * TILE_B) + ((ms & 1) * 4) * 1024 + l * 16;

  f32x16 acc[4][2] = {};

  for (int ks = 0; ks < 12; ++ks) {
    if (ks < 11) BLOAD(ks + 1);  // T14: issue next-ks B loads first

    const char* at = abase + ks * TILE_B;
    const char* bt = (const char*)lds + (ks & 1) * 16384 + nh * 2048 + l * 16;

#pragma unroll
    for (int kk = 0; kk < 4; ++kk) {
      bf16x8 b0 = *(const bf16x8*)(bt + kk * 4096);
      bf16x8 b1 = *(const bf16x8*)(bt + kk * 4096 + 1024);
      bf16x8 a0 = *(const bf16x8*)(at + kk * 8192);
      bf16x8 a1 = *(const bf16x8*)(at + kk * 8192 + 1024);
      bf16x8 a2 = *(const bf16x8*)(at + kk * 8192 + 2048);
      bf16x8 a3 = *(const bf16x8*)(at + kk * 8192 + 3072);
      __builtin_amdgcn_s_setprio(1);
      acc[0][0] = __builtin_amdgcn_mfma_f32_32x32x16_bf16(a0, b0, acc[0][0], 0, 0, 0);
      acc[0][1] = __builtin_amdgcn_mfma_f32_32x32x16_bf16(a0, b1, acc[0][1], 0, 0, 0);
      acc[1][0] = __builtin_amdgcn_mfma_f32_32x32x16_bf16(a1, b0, acc[1][0], 0, 0, 0);
      acc[1][1] = __builtin_amdgcn_mfma_f32_32x32x16_bf16(a1, b1, acc[1][1], 0, 0, 0);
      acc[2][0] = __builtin_amdgcn_mfma_f32_32x32x16_bf16(a2, b0, acc[2][0], 0, 0, 0);
      acc[2][1] = __builtin_amdgcn_mfma_f32_32x32x16_bf16(a2, b1, acc[2][1], 0, 0, 0);
      acc[3][0] = __builtin_amdgcn_mfma_f32_32x32x16_bf16(a3, b0, acc[3][0], 0, 0, 0);
      acc[3][1] = __builtin_amdgcn_mfma_f32_32x32x16_bf16(a3, b1, acc[3][1], 0, 0, 0);
      __builtin_amdgcn_s_setprio(0);
    }

    if (ks < 11) BSTORE((ks + 1) & 1);  // br consumed -> VMEM retired
    __syncthreads();                     // drain is ~free (see header)
  }
#undef BLOAD
#undef BSTORE

  // epilogue: C layout col=lane&31, row=(reg&3)+8*(reg>>2)+4*(lane>>5)
  const int lh = l >> 5;
#pragma unroll
  for (int nr = 0; nr < 2; ++nr) {
    const int gc = n0 + (nh * 2 + nr) * 32 + (l & 31);
    if (gc < NCOLS) {
#pragma unroll
      for (int mr = 0; mr < 4; ++mr)
#pragma unroll
        for (int reg = 0; reg < 16; ++reg) {
          const int row = mt * 512 + ms * 128 + mr * 32 +
                          (reg & 3) + 8 * (reg >> 2) + 4 * lh;
          out[(size_t)row * NCOLS + gc] = acc[mr][nr][reg];
        }
    }
  }
}

extern "C" void kernel_launch(void* const* d_in, const int* in_sizes, int n_in,
                              void* d_out, int out_size, void* d_ws, size_t ws_size,
                              hipStream_t stream) {
  const int*   ids       = (const int*)d_in[0];
  const float* W_emb     = (const float*)d_in[1];
  const float* W_rev     = (const float*)d_in[2];
  const float* padding   = (const float*)d_in[3];
  const int*   syn_table = (const int*)d_in[4];
  const int*   syn_mask  = (const int*)d_in[5];
  float* out = (float*)d_out;
  char*  ws  = (char*)d_ws;

  // A tiles in ws[0, 1.5MB)
  hipLaunchKernelGGL(emb_kernel, dim3(NROWS), dim3(256), 0, stream,
                     ids, W_emb, padding, syn_table, syn_mask, ws);

  hipLaunchKernelGGL(gemm_fused, dim3(NWG), dim3(512), 0, stream,
                     W_rev, ws, out);
}